// Round 2
// baseline (271.647 us; speedup 1.0000x reference)
//
#include <hip/hip_runtime.h>

#define NBLOCKS 2048
#define NTHREADS 256
// Per-tile: NTHREADS threads x 4 float4 = 1024 float4 = 16 KB per array.
#define TILE_V4 (NTHREADS * 4)

typedef float vf4 __attribute__((ext_vector_type(4)));

// Pure streaming kernel — m13-pattern (6.29 TB/s measured on this chip).
// No LDS staging (y has zero reuse), no barriers, no DMA, no nontemporal.
// 8 x dwordx4 loads in flight per thread-iteration; 32 waves/CU of TLP
// hide HBM latency. Count goes through ballot -> s_bcnt1 (scalar pipe).
__global__ __launch_bounds__(NTHREADS, 8) void loss1_partial(
    const float* __restrict__ x, const float* __restrict__ y,
    long long n, float* __restrict__ psum, int* __restrict__ pcnt) {
    const long long nvec = n >> 2;
    const long long ntiles = nvec / TILE_V4;
    const vf4* __restrict__ x4 = (const vf4*)x;
    const vf4* __restrict__ y4 = (const vf4*)y;

    float s  = 0.0f;
    int   cw = 0;   // wave-uniform count (ballot/popcount)
    int   ct = 0;   // per-lane count (tail path only)

    for (long long t = blockIdx.x; t < ntiles; t += gridDim.x) {
        long long p = t * TILE_V4 + threadIdx.x;

        vf4 a0 = x4[p];
        vf4 a1 = x4[p + NTHREADS];
        vf4 a2 = x4[p + 2 * NTHREADS];
        vf4 a3 = x4[p + 3 * NTHREADS];
        vf4 b0 = y4[p];
        vf4 b1 = y4[p + NTHREADS];
        vf4 b2 = y4[p + 2 * NTHREADS];
        vf4 b3 = y4[p + 3 * NTHREADS];

        #pragma unroll
        for (int k = 0; k < 4; ++k) {
            s += fmaxf(a0[k] - b0[k], 0.0f);
            s += fmaxf(a1[k] - b1[k], 0.0f);
            s += fmaxf(a2[k] - b2[k], 0.0f);
            s += fmaxf(a3[k] - b3[k], 0.0f);
            cw += (int)__popcll(__ballot(a0[k] > b0[k]));
            cw += (int)__popcll(__ballot(a1[k] > b1[k]));
            cw += (int)__popcll(__ballot(a2[k] > b2[k]));
            cw += (int)__popcll(__ballot(a3[k] > b3[k]));
        }
    }

    // float4 tail beyond the last full tile (none for this shape)
    {
        long long gtid = (long long)blockIdx.x * blockDim.x + threadIdx.x;
        long long gstride = (long long)gridDim.x * blockDim.x;
        for (long long i = ntiles * TILE_V4 + gtid; i < nvec; i += gstride) {
            vf4 a = x4[i];
            vf4 b = y4[i];
            #pragma unroll
            for (int k = 0; k < 4; ++k) {
                s += (a[k] > b[k]) ? (a[k] - b[k]) : 0.0f;  ct += (a[k] > b[k]);
            }
        }
        if (gtid == 0) {
            for (long long j = nvec << 2; j < n; ++j) {
                float d = x[j] - y[j];
                if (x[j] > y[j]) { s += d; ct += 1; }
            }
        }
    }

    // wave-64 shuffle reduction (s and per-lane tail count only;
    // cw is already wave-uniform — added once by lane 0 below)
    #pragma unroll
    for (int off = 32; off > 0; off >>= 1) {
        s  += __shfl_down(s, off, 64);
        ct += __shfl_down(ct, off, 64);
    }

    __shared__ float ss[NTHREADS / 64];
    __shared__ int   sc[NTHREADS / 64];
    int lane = threadIdx.x & 63;
    int wave = threadIdx.x >> 6;
    if (lane == 0) { ss[wave] = s; sc[wave] = ct + cw; }
    __syncthreads();
    if (threadIdx.x == 0) {
        float ts = 0.0f; int tc = 0;
        #pragma unroll
        for (int w = 0; w < NTHREADS / 64; ++w) { ts += ss[w]; tc += sc[w]; }
        psum[blockIdx.x] = ts;
        pcnt[blockIdx.x] = tc;
    }
}

__global__ __launch_bounds__(1024) void loss1_final(
    const float* __restrict__ psum, const int* __restrict__ pcnt,
    int nparts, float* __restrict__ out) {
    int tid = threadIdx.x;
    float s = 0.0f;
    int c = 0;
    for (int i = tid; i < nparts; i += 1024) {
        s += psum[i];
        c += pcnt[i];
    }
    #pragma unroll
    for (int off = 32; off > 0; off >>= 1) {
        s += __shfl_down(s, off, 64);
        c += __shfl_down(c, off, 64);
    }
    __shared__ float ss[16];
    __shared__ int   sc[16];
    int lane = tid & 63;
    int wave = tid >> 6;
    if (lane == 0) { ss[wave] = s; sc[wave] = c; }
    __syncthreads();
    if (tid == 0) {
        float ts = 0.0f; int tc = 0;
        #pragma unroll
        for (int w = 0; w < 16; ++w) { ts += ss[w]; tc += sc[w]; }
        out[0] = (tc > 0) ? (ts / (float)tc) : 0.0f;
    }
}

extern "C" void kernel_launch(void* const* d_in, const int* in_sizes, int n_in,
                              void* d_out, int out_size, void* d_ws, size_t ws_size,
                              hipStream_t stream) {
    const float* x = (const float*)d_in[0];
    const float* y = (const float*)d_in[1];
    long long n = (long long)in_sizes[0];

    float* psum = (float*)d_ws;
    int*   pcnt = (int*)((char*)d_ws + NBLOCKS * sizeof(float));

    loss1_partial<<<NBLOCKS, NTHREADS, 0, stream>>>(x, y, n, psum, pcnt);
    loss1_final<<<1, 1024, 0, stream>>>(psum, pcnt, NBLOCKS, (float*)d_out);
}

// Round 3
// 259.976 us; speedup vs baseline: 1.0449x; 1.0449x over previous
//
#include <hip/hip_runtime.h>

#define NBLOCKS 2048
#define NTHREADS 256
// Per-tile: NTHREADS threads x 4 float4 = 1024 float4 = 16 KB per array.
#define TILE_V4 (NTHREADS * 4)

typedef float vf4 __attribute__((ext_vector_type(4)));

// Cache-partitioned streaming kernel:
//   x -> nontemporal loads (no-allocate: streams from HBM, never touches L3)
//   y -> plain loads (134 MB alone fits the 256 MB Infinity Cache -> stays hit)
// This avoids the R2 failure mode where both 134 MB streams thrash the 256 MB
// L3 (268 MB combined working set -> steady-state alloc/evict churn).
// No LDS staging (zero reuse), no barriers; 32 waves/CU of TLP hide latency.
__global__ __launch_bounds__(NTHREADS, 8) void loss1_partial(
    const float* __restrict__ x, const float* __restrict__ y,
    long long n, float* __restrict__ psum, int* __restrict__ pcnt) {
    const long long nvec = n >> 2;
    const long long ntiles = nvec / TILE_V4;
    const vf4* __restrict__ x4 = (const vf4*)x;
    const vf4* __restrict__ y4 = (const vf4*)y;

    float s  = 0.0f;
    int   cw = 0;   // wave-uniform count (ballot/popcount)
    int   ct = 0;   // per-lane count (tail path only)

    for (long long t = blockIdx.x; t < ntiles; t += gridDim.x) {
        long long p = t * TILE_V4 + threadIdx.x;

        vf4 a0 = __builtin_nontemporal_load(&x4[p]);
        vf4 a1 = __builtin_nontemporal_load(&x4[p + NTHREADS]);
        vf4 a2 = __builtin_nontemporal_load(&x4[p + 2 * NTHREADS]);
        vf4 a3 = __builtin_nontemporal_load(&x4[p + 3 * NTHREADS]);
        vf4 b0 = y4[p];
        vf4 b1 = y4[p + NTHREADS];
        vf4 b2 = y4[p + 2 * NTHREADS];
        vf4 b3 = y4[p + 3 * NTHREADS];

        #pragma unroll
        for (int k = 0; k < 4; ++k) {
            s += fmaxf(a0[k] - b0[k], 0.0f);
            s += fmaxf(a1[k] - b1[k], 0.0f);
            s += fmaxf(a2[k] - b2[k], 0.0f);
            s += fmaxf(a3[k] - b3[k], 0.0f);
            cw += (int)__popcll(__ballot(a0[k] > b0[k]));
            cw += (int)__popcll(__ballot(a1[k] > b1[k]));
            cw += (int)__popcll(__ballot(a2[k] > b2[k]));
            cw += (int)__popcll(__ballot(a3[k] > b3[k]));
        }
    }

    // float4 tail beyond the last full tile (none for this shape)
    {
        long long gtid = (long long)blockIdx.x * blockDim.x + threadIdx.x;
        long long gstride = (long long)gridDim.x * blockDim.x;
        for (long long i = ntiles * TILE_V4 + gtid; i < nvec; i += gstride) {
            vf4 a = x4[i];
            vf4 b = y4[i];
            #pragma unroll
            for (int k = 0; k < 4; ++k) {
                s += (a[k] > b[k]) ? (a[k] - b[k]) : 0.0f;  ct += (a[k] > b[k]);
            }
        }
        if (gtid == 0) {
            for (long long j = nvec << 2; j < n; ++j) {
                float d = x[j] - y[j];
                if (x[j] > y[j]) { s += d; ct += 1; }
            }
        }
    }

    // wave-64 shuffle reduction (s and per-lane tail count only;
    // cw is already wave-uniform — added once by lane 0 below)
    #pragma unroll
    for (int off = 32; off > 0; off >>= 1) {
        s  += __shfl_down(s, off, 64);
        ct += __shfl_down(ct, off, 64);
    }

    __shared__ float ss[NTHREADS / 64];
    __shared__ int   sc[NTHREADS / 64];
    int lane = threadIdx.x & 63;
    int wave = threadIdx.x >> 6;
    if (lane == 0) { ss[wave] = s; sc[wave] = ct + cw; }
    __syncthreads();
    if (threadIdx.x == 0) {
        float ts = 0.0f; int tc = 0;
        #pragma unroll
        for (int w = 0; w < NTHREADS / 64; ++w) { ts += ss[w]; tc += sc[w]; }
        psum[blockIdx.x] = ts;
        pcnt[blockIdx.x] = tc;
    }
}

__global__ __launch_bounds__(1024) void loss1_final(
    const float* __restrict__ psum, const int* __restrict__ pcnt,
    int nparts, float* __restrict__ out) {
    int tid = threadIdx.x;
    float s = 0.0f;
    int c = 0;
    for (int i = tid; i < nparts; i += 1024) {
        s += psum[i];
        c += pcnt[i];
    }
    #pragma unroll
    for (int off = 32; off > 0; off >>= 1) {
        s += __shfl_down(s, off, 64);
        c += __shfl_down(c, off, 64);
    }
    __shared__ float ss[16];
    __shared__ int   sc[16];
    int lane = tid & 63;
    int wave = tid >> 6;
    if (lane == 0) { ss[wave] = s; sc[wave] = c; }
    __syncthreads();
    if (tid == 0) {
        float ts = 0.0f; int tc = 0;
        #pragma unroll
        for (int w = 0; w < 16; ++w) { ts += ss[w]; tc += sc[w]; }
        out[0] = (tc > 0) ? (ts / (float)tc) : 0.0f;
    }
}

extern "C" void kernel_launch(void* const* d_in, const int* in_sizes, int n_in,
                              void* d_out, int out_size, void* d_ws, size_t ws_size,
                              hipStream_t stream) {
    const float* x = (const float*)d_in[0];
    const float* y = (const float*)d_in[1];
    long long n = (long long)in_sizes[0];

    float* psum = (float*)d_ws;
    int*   pcnt = (int*)((char*)d_ws + NBLOCKS * sizeof(float));

    loss1_partial<<<NBLOCKS, NTHREADS, 0, stream>>>(x, y, n, psum, pcnt);
    loss1_final<<<1, 1024, 0, stream>>>(psum, pcnt, NBLOCKS, (float*)d_out);
}

// Round 4
// 259.694 us; speedup vs baseline: 1.0460x; 1.0011x over previous
//
#include <hip/hip_runtime.h>

#define NBLOCKS 2048
#define NTHREADS 256
// Per-tile: NTHREADS threads x 4 float4 = 1024 float4 = 16 KB per array.
#define TILE_V4 (NTHREADS * 4)

typedef float vf4 __attribute__((ext_vector_type(4)));

// Register-pipelined streaming kernel (depth-1 prefetch, no LDS, no barriers):
//   - issue tile t+1's 8 dwordx4 loads BEFORE computing tile t, so every wave
//     keeps >=8 loads in flight through its compute phase (no duty-cycle drain;
//     compiler waits at vmcnt(8), not vmcnt(0), in the steady-state loop).
//   - x -> nontemporal (no L3 allocate, streams from HBM)
//   - y -> plain loads (134 MB alone fits 256 MB L3, stays resident)
//   - count via ballot -> s_bcnt1 on the scalar pipe.
__global__ __launch_bounds__(NTHREADS, 4) void loss1_partial(
    const float* __restrict__ x, const float* __restrict__ y,
    long long n, float* __restrict__ psum, int* __restrict__ pcnt) {
    const long long nvec = n >> 2;
    const long long ntiles = nvec / TILE_V4;
    const vf4* __restrict__ x4 = (const vf4*)x;
    const vf4* __restrict__ y4 = (const vf4*)y;

    float s  = 0.0f;
    int   cw = 0;   // wave-uniform count (ballot/popcount)
    int   ct = 0;   // per-lane count (tail path only)

    long long t = blockIdx.x;
    bool have = (t < ntiles);
    vf4 a0, a1, a2, a3, b0, b1, b2, b3;

    if (have) {
        long long p = t * TILE_V4 + threadIdx.x;
        a0 = __builtin_nontemporal_load(&x4[p]);
        b0 = y4[p];
        a1 = __builtin_nontemporal_load(&x4[p + NTHREADS]);
        b1 = y4[p + NTHREADS];
        a2 = __builtin_nontemporal_load(&x4[p + 2 * NTHREADS]);
        b2 = y4[p + 2 * NTHREADS];
        a3 = __builtin_nontemporal_load(&x4[p + 3 * NTHREADS]);
        b3 = y4[p + 3 * NTHREADS];
    }

    while (have) {
        const long long tn = t + gridDim.x;
        const bool haven = (tn < ntiles);

        // Prefetch next tile into fresh registers before touching a*/b*:
        // these 8 loads stay outstanding across the compute below.
        vf4 na0, na1, na2, na3, nb0, nb1, nb2, nb3;
        if (haven) {
            long long pn = tn * TILE_V4 + threadIdx.x;
            na0 = __builtin_nontemporal_load(&x4[pn]);
            nb0 = y4[pn];
            na1 = __builtin_nontemporal_load(&x4[pn + NTHREADS]);
            nb1 = y4[pn + NTHREADS];
            na2 = __builtin_nontemporal_load(&x4[pn + 2 * NTHREADS]);
            nb2 = y4[pn + 2 * NTHREADS];
            na3 = __builtin_nontemporal_load(&x4[pn + 3 * NTHREADS]);
            nb3 = y4[pn + 3 * NTHREADS];
        }

        #pragma unroll
        for (int k = 0; k < 4; ++k) {
            s += fmaxf(a0[k] - b0[k], 0.0f);
            s += fmaxf(a1[k] - b1[k], 0.0f);
            s += fmaxf(a2[k] - b2[k], 0.0f);
            s += fmaxf(a3[k] - b3[k], 0.0f);
            cw += (int)__popcll(__ballot(a0[k] > b0[k]));
            cw += (int)__popcll(__ballot(a1[k] > b1[k]));
            cw += (int)__popcll(__ballot(a2[k] > b2[k]));
            cw += (int)__popcll(__ballot(a3[k] > b3[k]));
        }

        if (haven) {
            a0 = na0; a1 = na1; a2 = na2; a3 = na3;
            b0 = nb0; b1 = nb1; b2 = nb2; b3 = nb3;
        }
        t = tn;
        have = haven;
    }

    // float4 tail beyond the last full tile (none for this shape)
    {
        long long gtid = (long long)blockIdx.x * blockDim.x + threadIdx.x;
        long long gstride = (long long)gridDim.x * blockDim.x;
        for (long long i = ntiles * TILE_V4 + gtid; i < nvec; i += gstride) {
            vf4 a = x4[i];
            vf4 b = y4[i];
            #pragma unroll
            for (int k = 0; k < 4; ++k) {
                s += (a[k] > b[k]) ? (a[k] - b[k]) : 0.0f;  ct += (a[k] > b[k]);
            }
        }
        if (gtid == 0) {
            for (long long j = nvec << 2; j < n; ++j) {
                float d = x[j] - y[j];
                if (x[j] > y[j]) { s += d; ct += 1; }
            }
        }
    }

    // wave-64 shuffle reduction (s and per-lane tail count only;
    // cw is already wave-uniform — added once by lane 0 below)
    #pragma unroll
    for (int off = 32; off > 0; off >>= 1) {
        s  += __shfl_down(s, off, 64);
        ct += __shfl_down(ct, off, 64);
    }

    __shared__ float ss[NTHREADS / 64];
    __shared__ int   sc[NTHREADS / 64];
    int lane = threadIdx.x & 63;
    int wave = threadIdx.x >> 6;
    if (lane == 0) { ss[wave] = s; sc[wave] = ct + cw; }
    __syncthreads();
    if (threadIdx.x == 0) {
        float ts = 0.0f; int tc = 0;
        #pragma unroll
        for (int w = 0; w < NTHREADS / 64; ++w) { ts += ss[w]; tc += sc[w]; }
        psum[blockIdx.x] = ts;
        pcnt[blockIdx.x] = tc;
    }
}

__global__ __launch_bounds__(1024) void loss1_final(
    const float* __restrict__ psum, const int* __restrict__ pcnt,
    int nparts, float* __restrict__ out) {
    int tid = threadIdx.x;
    float s = 0.0f;
    int c = 0;
    for (int i = tid; i < nparts; i += 1024) {
        s += psum[i];
        c += pcnt[i];
    }
    #pragma unroll
    for (int off = 32; off > 0; off >>= 1) {
        s += __shfl_down(s, off, 64);
        c += __shfl_down(c, off, 64);
    }
    __shared__ float ss[16];
    __shared__ int   sc[16];
    int lane = tid & 63;
    int wave = tid >> 6;
    if (lane == 0) { ss[wave] = s; sc[wave] = c; }
    __syncthreads();
    if (tid == 0) {
        float ts = 0.0f; int tc = 0;
        #pragma unroll
        for (int w = 0; w < 16; ++w) { ts += ss[w]; tc += sc[w]; }
        out[0] = (tc > 0) ? (ts / (float)tc) : 0.0f;
    }
}

extern "C" void kernel_launch(void* const* d_in, const int* in_sizes, int n_in,
                              void* d_out, int out_size, void* d_ws, size_t ws_size,
                              hipStream_t stream) {
    const float* x = (const float*)d_in[0];
    const float* y = (const float*)d_in[1];
    long long n = (long long)in_sizes[0];

    float* psum = (float*)d_ws;
    int*   pcnt = (int*)((char*)d_ws + NBLOCKS * sizeof(float));

    loss1_partial<<<NBLOCKS, NTHREADS, 0, stream>>>(x, y, n, psum, pcnt);
    loss1_final<<<1, 1024, 0, stream>>>(psum, pcnt, NBLOCKS, (float*)d_out);
}